// Round 5
// baseline (337.671 us; speedup 1.0000x reference)
//
#include <hip/hip_runtime.h>
#include <hip/hip_bf16.h>

typedef __bf16 bf16;
typedef __bf16 bf16x8 __attribute__((ext_vector_type(8)));
typedef float f32x4 __attribute__((ext_vector_type(4)));

// ---------------- async global->LDS (width 16) ----------------
__device__ __forceinline__ void gload_lds16(const bf16* g, bf16* l) {
    __builtin_amdgcn_global_load_lds(
        (const __attribute__((address_space(1))) void*)g,
        (__attribute__((address_space(3))) void*)l, 16, 0, 0);
}

// ---------------- GroupNorm stats: one block per (n,group) ----------------
__global__ __launch_bounds__(256) void k_gnstats(const float* __restrict__ x,
                                                 float2* __restrict__ stats) {
    const int g = blockIdx.x;            // 0..127
    const float4* p = (const float4*)(x + (long)g * 65536);
    float s = 0.f, ss = 0.f;
    #pragma unroll 8
    for (int i = 0; i < 64; ++i) {
        float4 v = p[threadIdx.x + i * 256];
        s  += v.x + v.y + v.z + v.w;
        ss += v.x * v.x + v.y * v.y + v.z * v.z + v.w * v.w;
    }
    #pragma unroll
    for (int off = 32; off >= 1; off >>= 1) {
        s  += __shfl_down(s, off);
        ss += __shfl_down(ss, off);
    }
    __shared__ float rs[4], rss[4];
    if ((threadIdx.x & 63) == 0) { rs[threadIdx.x >> 6] = s; rss[threadIdx.x >> 6] = ss; }
    __syncthreads();
    if (threadIdx.x == 0) {
        float S  = rs[0] + rs[1] + rs[2] + rs[3];
        float SS = rss[0] + rss[1] + rss[2] + rss[3];
        float mu = S * (1.f / 65536.f);
        float var = SS * (1.f / 65536.f) - mu * mu;
        stats[g] = make_float2(mu, rsqrtf(var + 1e-5f));
    }
}

// ---------------- normalize + transpose NCHW -> tokens [nt][512] bf16 ----------------
__global__ __launch_bounds__(256) void k_norm_t(const float* __restrict__ x,
                                                const float* __restrict__ w,
                                                const float* __restrict__ b,
                                                const float2* __restrict__ stats,
                                                bf16* __restrict__ t) {
    __shared__ float tile[64][65];
    const int bid = blockIdx.x;
    const int n = bid >> 9, rem = bid & 511;
    const int s0 = (rem >> 3) * 64, c0 = (rem & 7) * 64;
    const int tid = threadIdx.x;
    const int sl = tid & 63, cq = tid >> 6;
    #pragma unroll
    for (int i = 0; i < 16; ++i) {
        const int cl = cq * 16 + i;
        const int c = c0 + cl;
        const float2 st = stats[n * 32 + (c >> 4)];
        const float v = x[((long)(n * 512 + c)) * 4096 + s0 + sl];
        tile[cl][sl] = (v - st.x) * st.y * w[c] + b[c];
    }
    __syncthreads();
    #pragma unroll
    for (int i = 0; i < 16; ++i) {
        const int sl2 = cq * 16 + i;
        const int cl2 = tid & 63;
        t[((long)(n * 4096 + s0 + sl2)) * 512 + c0 + cl2] = (bf16)tile[cl2][sl2];
    }
}

// ---------------- weight conversion (fold log2e/sqrt(512) into q rows) ----------------
__global__ __launch_bounds__(256) void k_convw(const float* __restrict__ qw,
                                               const float* __restrict__ pw,
                                               bf16* __restrict__ qwb,
                                               bf16* __restrict__ pwb) {
    const int i = blockIdx.x * 256 + threadIdx.x;
    if (i < 786432) {
        float v = qw[i];
        if (i < 512 * 512) v *= 0.06376281516217733f;  // log2(e)/sqrt(512)
        qwb[i] = (bf16)v;
    } else {
        const int j = i - 786432;
        pwb[j] = (bf16)pw[j];
    }
}

// ---------------- transpose v-part of qkv -> Vt[n][512][4096] ----------------
__global__ __launch_bounds__(256) void k_vt(const bf16* __restrict__ qkv,
                                            bf16* __restrict__ Vt) {
    __shared__ bf16 tile[64][66];
    const int bid = blockIdx.x;
    const int n = bid >> 9, rem = bid & 511;
    const int s0 = (rem >> 3) * 64, d0 = (rem & 7) * 64;
    const int tid = threadIdx.x;
    #pragma unroll
    for (int i = 0; i < 16; ++i) {
        const int sl = (tid >> 6) * 16 + i;
        const int dl = tid & 63;
        tile[sl][dl] = qkv[((long)(n * 4096 + s0 + sl)) * 1536 + 1024 + d0 + dl];
    }
    __syncthreads();
    #pragma unroll
    for (int i = 0; i < 16; ++i) {
        const int dl = (tid >> 6) * 16 + i;
        const int sl = tid & 63;
        Vt[((long)(n * 512 + d0 + dl)) * 4096 + s0 + sl] = tile[sl][dl];
    }
}

// =====================================================================
// Fused flash-PV, split-D: each block does 64 S-rows x 256 D-cols.
// 4 waves, 256 threads, LDS ~74KB -> 2 blocks/CU (16 waves/CU overlap).
// S read per half (2x logical read; L3-resident so HBM ~1x).
// LDS: Bs dbuf 64KB (gload_lds, pre-swizzled src), As 8KB, sstat 64 f32.
// =====================================================================
__global__ __launch_bounds__(256, 2) void k_flashpv(
    const bf16* __restrict__ S, const bf16* __restrict__ Vt,
    bf16* __restrict__ O) {
    __shared__ bf16 Bs[2][256 * 64];
    __shared__ bf16 As[64 * 64];
    __shared__ float sstat[64];
    const int t = threadIdx.x;
    const int w = t >> 6, l = t & 63, lr = l & 15, lg = l >> 4;
    const int r = t >> 2, c4 = t & 3, r7 = r & 7;   // S: row r(0..63), 16 cols at c4*16
    const int vr = t >> 3, vc8 = t & 7, vr7 = vr & 7; // V staging: 32 rows/unit
    const int lr7 = lr & 7;
    const long z = blockIdx.z;
    const int bx = blockIdx.x;   // S row-tile
    const int dh = blockIdx.y;   // D half

    const bf16* Sg = S + z * ((long)4096 * 4096) + (long)(bx * 64 + r) * 4096 + c4 * 16;
    const bf16* Vg = Vt + z * ((long)512 * 4096) + (long)(dh * 256 + vr) * 4096 + (vc8 ^ vr7) * 8;

    auto issueB = [&](int tile, int buf) {
        bf16* lp = Bs[buf];
        #pragma unroll
        for (int u = 0; u < 8; ++u)
            gload_lds16(Vg + (long)u * 32 * 4096 + tile * 64, lp + u * 2048 + t * 8);
    };

    f32x4 acc[4][4];
    #pragma unroll
    for (int i = 0; i < 4; ++i)
        #pragma unroll
        for (int n = 0; n < 4; ++n) acc[i][n] = f32x4{0.f, 0.f, 0.f, 0.f};

    float m_run = -1e30f, l_run = 0.f;
    bf16x8 pa0, pa1;
    float scale = 0.f;

    auto stats = [&](bf16x8 sa, bf16x8 sb) {
        float fv[16];
        #pragma unroll
        for (int j = 0; j < 8; ++j) { fv[j] = (float)sa[j]; fv[8 + j] = (float)sb[j]; }
        float tmax = fv[0];
        #pragma unroll
        for (int j = 1; j < 16; ++j) tmax = fmaxf(tmax, fv[j]);
        tmax = fmaxf(tmax, __shfl_xor(tmax, 1));
        tmax = fmaxf(tmax, __shfl_xor(tmax, 2));
        float mnew, scl;
        if (tmax > m_run + 8.f) { mnew = tmax; scl = exp2f(m_run - tmax); }
        else                    { mnew = m_run; scl = 1.f; }
        float ts = 0.f;
        #pragma unroll
        for (int j = 0; j < 16; ++j) { fv[j] = exp2f(fv[j] - mnew); ts += fv[j]; }
        ts += __shfl_xor(ts, 1);
        ts += __shfl_xor(ts, 2);
        l_run = l_run * scl + ts;
        m_run = mnew;
        #pragma unroll
        for (int j = 0; j < 8; ++j) { pa0[j] = (bf16)fv[j]; pa1[j] = (bf16)fv[8 + j]; }
        scale = scl;
    };

    // ---- prologue: tile 0 ----
    bf16x8 sa0 = *(const bf16x8*)(Sg);
    bf16x8 sb0 = *(const bf16x8*)(Sg + 8);
    issueB(0, 0);
    stats(sa0, sb0);   // compiler-inserted wait covers S loads only

    for (int ti = 0; ti < 64; ++ti) {
        __builtin_amdgcn_s_barrier();          // prev compute-phase LDS reads done
        asm volatile("" ::: "memory");
        *(bf16x8*)(As + r * 64 + (((c4 * 2) ^ r7) * 8)) = pa0;
        *(bf16x8*)(As + r * 64 + (((c4 * 2 + 1) ^ r7) * 8)) = pa1;
        if (c4 == 0) sstat[r] = scale;
        bf16x8 sa, sb;
        if (ti < 63) {
            sa = *(const bf16x8*)(Sg + (ti + 1) * 64);
            sb = *(const bf16x8*)(Sg + (ti + 1) * 64 + 8);
            issueB(ti + 1, (ti + 1) & 1);
            // outstanding: B_ti(8) + S(2) + B_{ti+1}(8) -> drain oldest 8
            asm volatile("s_waitcnt vmcnt(10) lgkmcnt(0)" ::: "memory");
        } else {
            asm volatile("s_waitcnt vmcnt(0) lgkmcnt(0)" ::: "memory");
        }
        __builtin_amdgcn_sched_barrier(0);
        __builtin_amdgcn_s_barrier();
        asm volatile("" ::: "memory");

        // rescale accumulators (rare: defer-threshold 8 in log2 domain)
        #pragma unroll
        for (int mi = 0; mi < 4; ++mi) {
            float4 sc = *(const float4*)&sstat[mi * 16 + lg * 4];
            if (sc.x != 1.f || sc.y != 1.f || sc.z != 1.f || sc.w != 1.f) {
                f32x4 scv = {sc.x, sc.y, sc.z, sc.w};
                #pragma unroll
                for (int n = 0; n < 4; ++n) acc[mi][n] *= scv;
            }
        }

        const bf16* Bsb = Bs[ti & 1];
        __builtin_amdgcn_s_setprio(1);
        #pragma unroll
        for (int kk = 0; kk < 2; ++kk) {
            bf16x8 af[4], bf[4];
            #pragma unroll
            for (int mi = 0; mi < 4; ++mi)
                af[mi] = *(const bf16x8*)(As + (mi * 16 + lr) * 64 + (((kk * 4 + lg) ^ lr7) * 8));
            #pragma unroll
            for (int n = 0; n < 4; ++n)
                bf[n] = *(const bf16x8*)(Bsb + (w * 64 + n * 16 + lr) * 64 + (((kk * 4 + lg) ^ lr7) * 8));
            #pragma unroll
            for (int mi = 0; mi < 4; ++mi)
                #pragma unroll
                for (int n = 0; n < 4; ++n)
                    acc[mi][n] = __builtin_amdgcn_mfma_f32_16x16x32_bf16(af[mi], bf[n], acc[mi][n], 0, 0, 0);
        }
        __builtin_amdgcn_s_setprio(0);

        if (ti < 63) stats(sa, sb);   // for tile ti+1
    }

    // ---- epilogue: broadcast l, normalize, store ----
    __builtin_amdgcn_s_barrier();
    asm volatile("" ::: "memory");
    if (c4 == 0) sstat[r] = l_run;
    asm volatile("s_waitcnt lgkmcnt(0)" ::: "memory");
    __builtin_amdgcn_s_barrier();
    asm volatile("" ::: "memory");

    bf16* Oz = O + z * ((long)4096 * 512);
    #pragma unroll
    for (int mi = 0; mi < 4; ++mi) {
        float4 lv = *(const float4*)&sstat[mi * 16 + lg * 4];
        float inv0 = 1.f / lv.x, inv1 = 1.f / lv.y, inv2 = 1.f / lv.z, inv3 = 1.f / lv.w;
        #pragma unroll
        for (int n = 0; n < 4; ++n) {
            const long base = (long)(bx * 64 + mi * 16 + lg * 4) * 512 + dh * 256 + w * 64 + n * 16 + lr;
            Oz[base]           = (bf16)(acc[mi][n][0] * inv0);
            Oz[base + 512]     = (bf16)(acc[mi][n][1] * inv1);
            Oz[base + 1024]    = (bf16)(acc[mi][n][2] * inv2);
            Oz[base + 1536]    = (bf16)(acc[mi][n][3] * inv3);
        }
    }
}

// =====================================================================
// 256x256 tile, BK=64, 8-wave, 8-phase GEMM with counted vmcnt (T3+T4+T5)
// =====================================================================
#define PH(mh, kk, S_, WN)                                                         \
  {                                                                                \
    if ((mh) == 0) {                                                               \
      _Pragma("unroll")                                                            \
      for (int n = 0; n < 4; ++n) {                                                \
        int row = wn * 64 + n * 16 + lr;                                           \
        int cg = lg ^ (row & 3);                                                   \
        bfr[n] = *(const bf16x8*)(BsT + (kk) * 8192 + row * 32 + cg * 8);          \
      }                                                                            \
    }                                                                              \
    _Pragma("unroll")                                                              \
    for (int i = 0; i < 4; ++i) {                                                  \
      int row = wm * 128 + ((mh) * 4 + i) * 16 + lr;                               \
      int cg = lg ^ (row & 3);                                                     \
      af[i] = *(const bf16x8*)(AsT + (kk) * 8192 + row * 32 + cg * 8);             \
    }                                                                              \
    if ((S_) >= 0) issue_unit(S_);                                                 \
    __builtin_amdgcn_s_barrier();                                                  \
    asm volatile("" ::: "memory");                                                 \
    __builtin_amdgcn_s_setprio(1);                                                 \
    _Pragma("unroll")                                                              \
    for (int i = 0; i < 4; ++i)                                                    \
      _Pragma("unroll")                                                            \
      for (int n = 0; n < 4; ++n)                                                  \
        acc[(mh) * 4 + i][n] =                                                     \
            __builtin_amdgcn_mfma_f32_16x16x32_bf16(af[i], bfr[n],                 \
                                                    acc[(mh) * 4 + i][n], 0, 0, 0);\
    __builtin_amdgcn_s_setprio(0);                                                 \
    if constexpr ((WN) >= 0)                                                       \
      asm volatile("s_waitcnt vmcnt(%0)" ::"i"(WN) : "memory");                    \
    __builtin_amdgcn_s_barrier();                                                  \
    asm volatile("" ::: "memory");                                                 \
  }

__global__ __launch_bounds__(512, 2) void gemm256(
    const bf16* __restrict__ A, int lda, long aZ,
    const bf16* __restrict__ B, int ldb, long bZ,
    bf16* __restrict__ C, int ldc, long cZ, int K) {
    __shared__ bf16 As[2 * 2 * 256 * 32];
    __shared__ bf16 Bs[2 * 2 * 256 * 32];
    const int t = threadIdx.x;
    const int wid = t >> 6, l = t & 63;
    const int wm = wid >> 2, wn = wid & 3;     // 2 x 4 waves
    const int lr = l & 15;
    const int lg = l >> 4;                     // fragment col-group 0..3
    const long z = blockIdx.z;

    const int gx = gridDim.x;
    int nwg = gx * gridDim.y;
    int flat = blockIdx.y * gx + blockIdx.x;
    if ((nwg & 7) == 0) { int qq = nwg >> 3; flat = (flat & 7) * qq + (flat >> 3); }
    const int bx = flat % gx, by = flat / gx;

    const bf16* Ab = A + z * aZ + (long)bx * 256 * lda;
    const bf16* Bb = B + z * bZ + (long)by * 256 * ldb;

    const int NT = K >> 6;
    const int NT4 = NT << 2;

    f32x4 acc[8][4];
    #pragma unroll
    for (int i = 0; i < 8; ++i)
        #pragma unroll
        for (int n = 0; n < 4; ++n) acc[i][n] = f32x4{0.f, 0.f, 0.f, 0.f};

    const int srow = t >> 2;       // 0..127
    const int scg0 = t & 3;

    auto issue_unit = [&](int s) {
        int ti = s >> 2, idx = s & 3;
        int kh = idx >> 1, isB = idx & 1;
        const bf16* g = isB ? Bb : Ab;
        int ld = isB ? ldb : lda;
        bf16* lp = (isB ? Bs : As) + ((ti & 1) * 2 + kh) * 8192;
        int k0 = ti * 64 + kh * 32;
        #pragma unroll
        for (int j = 0; j < 2; ++j) {
            int row = j * 128 + srow;
            int cg = scg0 ^ (row & 3);
            gload_lds16(g + (long)row * ld + k0 + cg * 8, lp + (j * 512 + t) * 8);
        }
    };

    #pragma unroll
    for (int s = 0; s < 6; ++s) issue_unit(s);
    asm volatile("s_waitcnt vmcnt(8)" ::: "memory");
    __builtin_amdgcn_s_barrier();
    asm volatile("" ::: "memory");

    bf16x8 bfr[4], af[4];

    for (int ti = 0; ti < NT - 2; ++ti) {
        const bf16* AsT = As + (ti & 1) * 16384;
        const bf16* BsT = Bs + (ti & 1) * 16384;
        const int sb = 4 * ti + 6;
        PH(0, 0, sb + 0, -1)
        PH(1, 0, sb + 1, 8)
        PH(0, 1, sb + 2, -1)
        PH(1, 1, sb + 3, 8)
    }
    {
        const bf16* AsT = As + ((NT - 2) & 1) * 16384;
        const bf16* BsT = Bs + ((NT - 2) & 1) * 16384;
        PH(0, 0, NT4 - 2, -1)
        PH(1, 0, NT4 - 1, 8)
        PH(0, 1, -1, -1)
        PH(1, 1, -1, 4)
    }
    {
        const bf16* AsT = As + ((NT - 1) & 1) * 16384;
        const bf16* BsT = Bs + ((NT - 1) & 1) * 16384;
        PH(0, 0, -1, -1)
        PH(1, 0, -1, 0)
        PH(0, 1, -1, -1)
        PH(1, 1, -1, -1)
    }

    const int row0 = bx * 256 + wm * 128;
    const int col0 = by * 256 + wn * 64;
    const int rq = lg * 4;
    bf16* Cz = C + z * cZ;
    #pragma unroll
    for (int i = 0; i < 8; ++i)
        #pragma unroll
        for (int n = 0; n < 4; ++n) {
            const int col = col0 + n * 16 + lr;
            #pragma unroll
            for (int r = 0; r < 4; ++r)
                Cz[(long)(row0 + i * 16 + rq + r) * ldc + col] = (bf16)acc[i][n][r];
        }
}

// =====================================================================
// 256x128 tile, BK=64, 8-wave (4M x 2N), 8-phase, counted vmcnt.
// EPI 0: bf16 store. EPI 2: f32 + bias store.
// =====================================================================
#define PH128(nh, kk, S_, WN)                                                      \
  {                                                                                \
    if ((nh) == 0) {                                                               \
      _Pragma("unroll")                                                            \
      for (int i = 0; i < 4; ++i) {                                                \
        int row = wm * 64 + i * 16 + lr;                                           \
        int cg = lg ^ (row & 3);                                                   \
        af[i] = *(const bf16x8*)(AsT + (kk) * 8192 + row * 32 + cg * 8);           \
      }                                                                            \
    }                                                                              \
    _Pragma("unroll")                                                              \
    for (int j = 0; j < 2; ++j) {                                                  \
      int row = wn * 64 + ((nh) * 2 + j) * 16 + lr;                                \
      int cg = lg ^ (row & 3);                                                     \
      bfr[j] = *(const bf16x8*)(BsT + (kk) * 4096 + row * 32 + cg * 8);            \
    }                                                                              \
    if ((S_) >= 0) issue_unit(S_);                                                 \
    __builtin_amdgcn_s_barrier();                                                  \
    asm volatile("" ::: "memory");                                                 \
    __builtin_amdgcn_s_setprio(1);                                                 \
    _Pragma("unroll")                                                              \
    for (int i = 0; i < 4; ++i)                                                    \
      _Pragma("unroll")                                                            \
      for (int j = 0; j < 2; ++j)                                                  \
        acc[i][(nh) * 2 + j] =                                                     \
            __builtin_amdgcn_mfma_f32_16x16x32_bf16(af[i], bfr[j],                 \
                                                    acc[i][(nh) * 2 + j], 0, 0, 0);\
    __builtin_amdgcn_s_setprio(0);                                                 \
    if constexpr ((WN) >= 0)                                                       \
      asm volatile("s_waitcnt vmcnt(%0)" ::"i"(WN) : "memory");                    \
    __builtin_amdgcn_s_barrier();                                                  \
    asm volatile("" ::: "memory");                                                 \
  }

template <int EPI>
__global__ __launch_bounds__(512, 2) void gemm_n128(
    const bf16* __restrict__ A, int lda, long aZ,
    const bf16* __restrict__ B, int ldb, long bZ,
    void* __restrict__ Cvp, int ldc, long cZ, int K,
    const float* __restrict__ bias) {
    __shared__ bf16 As[2 * 2 * 256 * 32];   // 64 KB
    __shared__ bf16 Bs[2 * 2 * 128 * 32];   // 32 KB
    const int t = threadIdx.x;
    const int wid = t >> 6, l = t & 63;
    const int wm = wid >> 1, wn = wid & 1;   // 4M x 2N waves, wave tile 64x64
    const int lr = l & 15;
    const int lg = l >> 4;
    const long z = blockIdx.z;

    const int gx = gridDim.x;
    int nwg = gx * gridDim.y;
    int flat = blockIdx.y * gx + blockIdx.x;
    if ((nwg & 7) == 0) { int qq = nwg >> 3; flat = (flat & 7) * qq + (flat >> 3); }
    const int bx = flat % gx, by = flat / gx;

    const bf16* Ab = A + z * aZ + (long)bx * 256 * lda;
    const bf16* Bb = B + z * bZ + (long)by * 128 * ldb;

    const int NT = K >> 6;
    const int NT4 = NT << 2;

    f32x4 acc[4][4];
    #pragma unroll
    for (int i = 0; i < 4; ++i)
        #pragma unroll
        for (int n = 0; n < 4; ++n) acc[i][n] = f32x4{0.f, 0.f, 0.f, 0.f};

    const int srow = t >> 2;       // 0..127
    const int scg0 = t & 3;

    auto issue_unit = [&](int s) {
        int ti = s >> 2, idx = s & 3;
        int kh = idx >> 1, isB = idx & 1;
        int k0 = ti * 64 + kh * 32;
        if (isB) {
            bf16* lp = Bs + ((ti & 1) * 2 + kh) * 4096;
            int cg = scg0 ^ (srow & 3);
            gload_lds16(Bb + (long)srow * ldb + k0 + cg * 8, lp + t * 8);
        } else {
            bf16* lp = As + ((ti & 1) * 2 + kh) * 8192;
            #pragma unroll
            for (int j = 0; j < 2; ++j) {
                int row = j * 128 + srow;
                int cg = scg0 ^ (row & 3);
                gload_lds16(Ab + (long)row * lda + k0 + cg * 8, lp + (j * 512 + t) * 8);
            }
        }
    };

    #pragma unroll
    for (int s = 0; s < 6; ++s) issue_unit(s);
    asm volatile("s_waitcnt vmcnt(6)" ::: "memory");
    __builtin_amdgcn_s_barrier();
    asm volatile("" ::: "memory");

    bf16x8 bfr[2], af[4];

    for (int ti = 0; ti < NT - 2; ++ti) {
        const bf16* AsT = As + (ti & 1) * 16384;
        const bf16* BsT = Bs + (ti & 1) * 8192;
        const int sb = 4 * ti + 6;
        PH128(0, 0, sb + 0, -1)
        PH128(1, 0, sb + 1, 6)
        PH128(0, 1, sb + 2, -1)
        PH128(1, 1, sb + 3, 6)
    }
    {
        const bf16* AsT = As + ((NT - 2) & 1) * 16384;
        const bf16* BsT = Bs + ((NT - 2) & 1) * 8192;
        PH128(0, 0, NT4 - 2, -1)
        PH128(1, 0, NT4 - 1, 6)
        PH128(0, 1, -1, -1)
        PH128(1, 1, -1, 3)
    }
    {
        const bf16* AsT = As + ((NT - 1) & 1) * 16384;
        const bf16* BsT = Bs + ((NT - 1) & 1) * 8192;
        PH128(0, 0, -1, -1)
        PH128(1, 0, -1, 0)
        PH128(0, 1, -1, -1)
        PH128(1, 1, -1, -1)
    }

    const int row0 = bx * 256 + wm * 64;
    const int col0 = by * 128 + wn * 64;
    const int rq = lg * 4;
    if (EPI == 2) {
        float* C = (float*)Cvp + z * cZ;
        #pragma unroll
        for (int i = 0; i < 4; ++i)
            #pragma unroll
            for (int n = 0; n < 4; ++n) {
                const int col = col0 + n * 16 + lr;
                #pragma unroll
                for (int r = 0; r < 4; ++r)
                    C[(long)(row0 + i * 16 + rq + r) * ldc + col] = acc[i][n][r] + bias[col];
            }
    } else {
        bf16* C = (bf16*)Cvp + z * cZ;
        #pragma unroll
        for (int i = 0; i < 4; ++i)
            #pragma unroll
            for (int n = 0; n < 4; ++n) {
                const int col = col0 + n * 16 + lr;
                #pragma unroll
                for (int r = 0; r < 4; ++r)
                    C[(long)(row0 + i * 16 + rq + r) * ldc + col] = (bf16)acc[i][n][r];
            }
    }
}

// ---------------- proj-out [nt][512] f32 -> NCHW + residual ----------------
__global__ __launch_bounds__(256) void k_final(const float* __restrict__ pb,
                                               const float* __restrict__ x,
                                               float* __restrict__ out) {
    __shared__ float tile[64][65];
    const int bid = blockIdx.x;
    const int n = bid >> 9, rem = bid & 511;
    const int s0 = (rem >> 3) * 64, c0 = (rem & 7) * 64;
    const int tid = threadIdx.x;
    #pragma unroll
    for (int i = 0; i < 16; ++i) {
        const int sl = (tid >> 6) * 16 + i;
        const int cl = tid & 63;
        tile[sl][cl] = pb[((long)(n * 4096 + s0 + sl)) * 512 + c0 + cl];
    }
    __syncthreads();
    #pragma unroll
    for (int i = 0; i < 16; ++i) {
        const int cl = (tid >> 6) * 16 + i;
        const int sl = tid & 63;
        const long oi = ((long)(n * 512 + c0 + cl)) * 4096 + s0 + sl;
        out[oi] = tile[sl][cl] + x[oi];
    }
}

extern "C" void kernel_launch(void* const* d_in, const int* in_sizes, int n_in,
                              void* d_out, int out_size, void* d_ws, size_t ws_size,
                              hipStream_t stream) {
    const float* x     = (const float*)d_in[0];
    const float* gnw   = (const float*)d_in[1];
    const float* gnb   = (const float*)d_in[2];
    const float* qkvw  = (const float*)d_in[3];
    const float* projw = (const float*)d_in[4];
    const float* projb = (const float*)d_in[5];

    char* ws = (char*)d_ws;
    size_t off = 0;
    auto alloc = [&](size_t bytes) {
        void* p = ws + off;
        off += (bytes + 255) & ~(size_t)255;
        return p;
    };
    bf16*   qwb   = (bf16*)alloc((size_t)1536 * 512 * 2);
    bf16*   pwb   = (bf16*)alloc((size_t)512 * 512 * 2);
    float2* stats = (float2*)alloc((size_t)128 * 8);
    bf16*   tbuf  = (bf16*)alloc((size_t)16384 * 512 * 2);   // tokens, later O
    bf16*   qkv   = (bf16*)alloc((size_t)16384 * 1536 * 2);
    bf16*   Vt    = (bf16*)alloc((size_t)4 * 512 * 4096 * 2);
    const size_t SSZ = (size_t)4096 * 4096 * 2;              // one batch of S (bf16)
    const size_t fixed = off;
    int g = 1;
    if (ws_size >= fixed + 4 * SSZ) g = 4;
    else if (ws_size >= fixed + 2 * SSZ) g = 2;
    bf16* Sbuf = (bf16*)alloc(g * SSZ);

    k_gnstats<<<128, 256, 0, stream>>>(x, stats);
    k_norm_t<<<2048, 256, 0, stream>>>(x, gnw, gnb, stats, tbuf);
    k_convw<<<4096, 256, 0, stream>>>(qkvw, projw, qwb, pwb);

    // qkv = t * qkvw^T   [16384 x 1536], 8-phase 256^2 kernel
    gemm256<<<dim3(64, 6, 1), 512, 0, stream>>>(
        tbuf, 512, 0, qwb, 512, 0, qkv, 1536, 0, 512);

    k_vt<<<2048, 256, 0, stream>>>(qkv, Vt);

    const long TS = (long)4096 * 1536;
    for (int g0 = 0; g0 < 4; g0 += g) {
        // S = q k^T (log2e & 1/sqrt(512) folded into q weights), bf16 out
        gemm256<<<dim3(16, 16, g), 512, 0, stream>>>(
            qkv + (long)g0 * TS, 1536, TS,
            qkv + (long)g0 * TS + 512, 1536, TS,
            Sbuf, 4096, (long)4096 * 4096, 512);
        // fused online-softmax + PV, split-D (2 blocks/CU)
        k_flashpv<<<dim3(64, 2, g), 256, 0, stream>>>(
            Sbuf, Vt + (long)g0 * 512 * 4096, tbuf + (long)g0 * 4096 * 512);
    }

    // proj: [16384 x 512] f32 + bias, into Sbuf (reused as f32 buffer)
    gemm_n128<2><<<dim3(64, 4, 1), 512, 0, stream>>>(
        tbuf, 512, 0, pwb, 512, 0, (float*)Sbuf, 512, 0, 512, projb);

    // transpose back + residual
    k_final<<<2048, 256, 0, stream>>>((float*)Sbuf, x, (float*)d_out);
}

// Round 6
// 312.502 us; speedup vs baseline: 1.0805x; 1.0805x over previous
//
#include <hip/hip_runtime.h>
#include <hip/hip_bf16.h>

typedef __bf16 bf16;
typedef __bf16 bf16x8 __attribute__((ext_vector_type(8)));
typedef float f32x4 __attribute__((ext_vector_type(4)));

// ---------------- async global->LDS (width 16) ----------------
__device__ __forceinline__ void gload_lds16(const bf16* g, bf16* l) {
    __builtin_amdgcn_global_load_lds(
        (const __attribute__((address_space(1))) void*)g,
        (__attribute__((address_space(3))) void*)l, 16, 0, 0);
}

// ---------------- GroupNorm stats: one block per (n,group) ----------------
__global__ __launch_bounds__(256) void k_gnstats(const float* __restrict__ x,
                                                 float2* __restrict__ stats) {
    const int g = blockIdx.x;            // 0..127
    const float4* p = (const float4*)(x + (long)g * 65536);
    float s = 0.f, ss = 0.f;
    #pragma unroll 8
    for (int i = 0; i < 64; ++i) {
        float4 v = p[threadIdx.x + i * 256];
        s  += v.x + v.y + v.z + v.w;
        ss += v.x * v.x + v.y * v.y + v.z * v.z + v.w * v.w;
    }
    #pragma unroll
    for (int off = 32; off >= 1; off >>= 1) {
        s  += __shfl_down(s, off);
        ss += __shfl_down(ss, off);
    }
    __shared__ float rs[4], rss[4];
    if ((threadIdx.x & 63) == 0) { rs[threadIdx.x >> 6] = s; rss[threadIdx.x >> 6] = ss; }
    __syncthreads();
    if (threadIdx.x == 0) {
        float S  = rs[0] + rs[1] + rs[2] + rs[3];
        float SS = rss[0] + rss[1] + rss[2] + rss[3];
        float mu = S * (1.f / 65536.f);
        float var = SS * (1.f / 65536.f) - mu * mu;
        stats[g] = make_float2(mu, rsqrtf(var + 1e-5f));
    }
}

// ---------------- normalize + transpose NCHW -> tokens [nt][512] bf16 ----------------
__global__ __launch_bounds__(256) void k_norm_t(const float* __restrict__ x,
                                                const float* __restrict__ w,
                                                const float* __restrict__ b,
                                                const float2* __restrict__ stats,
                                                bf16* __restrict__ t) {
    __shared__ float tile[64][65];
    const int bid = blockIdx.x;
    const int n = bid >> 9, rem = bid & 511;
    const int s0 = (rem >> 3) * 64, c0 = (rem & 7) * 64;
    const int tid = threadIdx.x;
    const int sl = tid & 63, cq = tid >> 6;
    #pragma unroll
    for (int i = 0; i < 16; ++i) {
        const int cl = cq * 16 + i;
        const int c = c0 + cl;
        const float2 st = stats[n * 32 + (c >> 4)];
        const float v = x[((long)(n * 512 + c)) * 4096 + s0 + sl];
        tile[cl][sl] = (v - st.x) * st.y * w[c] + b[c];
    }
    __syncthreads();
    #pragma unroll
    for (int i = 0; i < 16; ++i) {
        const int sl2 = cq * 16 + i;
        const int cl2 = tid & 63;
        t[((long)(n * 4096 + s0 + sl2)) * 512 + c0 + cl2] = (bf16)tile[cl2][sl2];
    }
}

// ---------------- weight conversion (fold log2e/sqrt(512) into q rows) ----------------
__global__ __launch_bounds__(256) void k_convw(const float* __restrict__ qw,
                                               const float* __restrict__ pw,
                                               bf16* __restrict__ qwb,
                                               bf16* __restrict__ pwb) {
    const int i = blockIdx.x * 256 + threadIdx.x;
    if (i < 786432) {
        float v = qw[i];
        if (i < 512 * 512) v *= 0.06376281516217733f;  // log2(e)/sqrt(512)
        qwb[i] = (bf16)v;
    } else {
        const int j = i - 786432;
        pwb[j] = (bf16)pw[j];
    }
}

// ---------------- transpose v-part of qkv -> Vt[n][512][4096] ----------------
__global__ __launch_bounds__(256) void k_vt(const bf16* __restrict__ qkv,
                                            bf16* __restrict__ Vt) {
    __shared__ bf16 tile[64][66];
    const int bid = blockIdx.x;
    const int n = bid >> 9, rem = bid & 511;
    const int s0 = (rem >> 3) * 64, d0 = (rem & 7) * 64;
    const int tid = threadIdx.x;
    #pragma unroll
    for (int i = 0; i < 16; ++i) {
        const int sl = (tid >> 6) * 16 + i;
        const int dl = tid & 63;
        tile[sl][dl] = qkv[((long)(n * 4096 + s0 + sl)) * 1536 + 1024 + d0 + dl];
    }
    __syncthreads();
    #pragma unroll
    for (int i = 0; i < 16; ++i) {
        const int dl = (tid >> 6) * 16 + i;
        const int sl = tid & 63;
        Vt[((long)(n * 512 + d0 + dl)) * 4096 + s0 + sl] = tile[sl][dl];
    }
}

// =====================================================================
// 256x256 tile, BK=64, 8-wave, 8-phase GEMM with counted vmcnt (T3+T4+T5)
// EPI 0: plain bf16 store. EPI 1: P = exp2(acc) bf16 store + per-col-tile
// row-sums into Lp[z][by][4096] (scores arrive in log2 domain).
// =====================================================================
#define PH(mh, kk, S_, WN)                                                         \
  {                                                                                \
    if ((mh) == 0) {                                                               \
      _Pragma("unroll")                                                            \
      for (int n = 0; n < 4; ++n) {                                                \
        int row = wn * 64 + n * 16 + lr;                                           \
        int cg = lg ^ (row & 3);                                                   \
        bfr[n] = *(const bf16x8*)(BsT + (kk) * 8192 + row * 32 + cg * 8);          \
      }                                                                            \
    }                                                                              \
    _Pragma("unroll")                                                              \
    for (int i = 0; i < 4; ++i) {                                                  \
      int row = wm * 128 + ((mh) * 4 + i) * 16 + lr;                               \
      int cg = lg ^ (row & 3);                                                     \
      af[i] = *(const bf16x8*)(AsT + (kk) * 8192 + row * 32 + cg * 8);             \
    }                                                                              \
    if ((S_) >= 0) issue_unit(S_);                                                 \
    __builtin_amdgcn_s_barrier();                                                  \
    asm volatile("" ::: "memory");                                                 \
    __builtin_amdgcn_s_setprio(1);                                                 \
    _Pragma("unroll")                                                              \
    for (int i = 0; i < 4; ++i)                                                    \
      _Pragma("unroll")                                                            \
      for (int n = 0; n < 4; ++n)                                                  \
        acc[(mh) * 4 + i][n] =                                                     \
            __builtin_amdgcn_mfma_f32_16x16x32_bf16(af[i], bfr[n],                 \
                                                    acc[(mh) * 4 + i][n], 0, 0, 0);\
    __builtin_amdgcn_s_setprio(0);                                                 \
    if constexpr ((WN) >= 0)                                                       \
      asm volatile("s_waitcnt vmcnt(%0)" ::"i"(WN) : "memory");                    \
    __builtin_amdgcn_s_barrier();                                                  \
    asm volatile("" ::: "memory");                                                 \
  }

template <int EPI>
__global__ __launch_bounds__(512, 2) void gemm256(
    const bf16* __restrict__ A, int lda, long aZ,
    const bf16* __restrict__ B, int ldb, long bZ,
    bf16* __restrict__ C, int ldc, long cZ, int K,
    float* __restrict__ Lp) {
    __shared__ bf16 As[2 * 2 * 256 * 32];
    __shared__ bf16 Bs[2 * 2 * 256 * 32];
    const int t = threadIdx.x;
    const int wid = t >> 6, l = t & 63;
    const int wm = wid >> 2, wn = wid & 3;     // 2 x 4 waves
    const int lr = l & 15;
    const int lg = l >> 4;                     // fragment col-group 0..3
    const long z = blockIdx.z;

    const int gx = gridDim.x;
    int nwg = gx * gridDim.y;
    int flat = blockIdx.y * gx + blockIdx.x;
    if ((nwg & 7) == 0) { int qq = nwg >> 3; flat = (flat & 7) * qq + (flat >> 3); }
    const int bx = flat % gx, by = flat / gx;

    const bf16* Ab = A + z * aZ + (long)bx * 256 * lda;
    const bf16* Bb = B + z * bZ + (long)by * 256 * ldb;

    const int NT = K >> 6;
    const int NT4 = NT << 2;

    f32x4 acc[8][4];
    #pragma unroll
    for (int i = 0; i < 8; ++i)
        #pragma unroll
        for (int n = 0; n < 4; ++n) acc[i][n] = f32x4{0.f, 0.f, 0.f, 0.f};

    const int srow = t >> 2;       // 0..127
    const int scg0 = t & 3;

    auto issue_unit = [&](int s) {
        int ti = s >> 2, idx = s & 3;
        int kh = idx >> 1, isB = idx & 1;
        const bf16* g = isB ? Bb : Ab;
        int ld = isB ? ldb : lda;
        bf16* lp = (isB ? Bs : As) + ((ti & 1) * 2 + kh) * 8192;
        int k0 = ti * 64 + kh * 32;
        #pragma unroll
        for (int j = 0; j < 2; ++j) {
            int row = j * 128 + srow;
            int cg = scg0 ^ (row & 3);
            gload_lds16(g + (long)row * ld + k0 + cg * 8, lp + (j * 512 + t) * 8);
        }
    };

    #pragma unroll
    for (int s = 0; s < 6; ++s) issue_unit(s);
    asm volatile("s_waitcnt vmcnt(8)" ::: "memory");
    __builtin_amdgcn_s_barrier();
    asm volatile("" ::: "memory");

    bf16x8 bfr[4], af[4];

    for (int ti = 0; ti < NT - 2; ++ti) {
        const bf16* AsT = As + (ti & 1) * 16384;
        const bf16* BsT = Bs + (ti & 1) * 16384;
        const int sb = 4 * ti + 6;
        PH(0, 0, sb + 0, -1)
        PH(1, 0, sb + 1, 8)
        PH(0, 1, sb + 2, -1)
        PH(1, 1, sb + 3, 8)
    }
    {
        const bf16* AsT = As + ((NT - 2) & 1) * 16384;
        const bf16* BsT = Bs + ((NT - 2) & 1) * 16384;
        PH(0, 0, NT4 - 2, -1)
        PH(1, 0, NT4 - 1, 8)
        PH(0, 1, -1, -1)
        PH(1, 1, -1, 4)
    }
    {
        const bf16* AsT = As + ((NT - 1) & 1) * 16384;
        const bf16* BsT = Bs + ((NT - 1) & 1) * 16384;
        PH(0, 0, -1, -1)
        PH(1, 0, -1, 0)
        PH(0, 1, -1, -1)
        PH(1, 1, -1, -1)
    }

    const int row0 = bx * 256 + wm * 128;
    const int col0 = by * 256 + wn * 64;
    const int rq = lg * 4;
    bf16* Cz = C + z * cZ;

    if (EPI == 1) {
        float rs[8][4];
        #pragma unroll
        for (int i = 0; i < 8; ++i)
            #pragma unroll
            for (int r = 0; r < 4; ++r) rs[i][r] = 0.f;
        #pragma unroll
        for (int i = 0; i < 8; ++i)
            #pragma unroll
            for (int n = 0; n < 4; ++n) {
                const int col = col0 + n * 16 + lr;
                #pragma unroll
                for (int r = 0; r < 4; ++r) {
                    float p = exp2f(acc[i][n][r]);
                    rs[i][r] += p;
                    Cz[(long)(row0 + i * 16 + rq + r) * ldc + col] = (bf16)p;
                }
            }
        // reduce partial row-sums across the 16 lr lanes (cols of this wave slice)
        #pragma unroll
        for (int i = 0; i < 8; ++i)
            #pragma unroll
            for (int r = 0; r < 4; ++r) {
                float s = rs[i][r];
                s += __shfl_xor(s, 1);
                s += __shfl_xor(s, 2);
                s += __shfl_xor(s, 4);
                s += __shfl_xor(s, 8);
                rs[i][r] = s;
            }
        float* lsf = (float*)As;   // reuse LDS (all tile reads done after last PH barrier)
        if (lr == 0) {
            #pragma unroll
            for (int i = 0; i < 8; ++i)
                #pragma unroll
                for (int r = 0; r < 4; ++r)
                    lsf[wn * 256 + wm * 128 + i * 16 + lg * 4 + r] = rs[i][r];
        }
        __syncthreads();
        if (t < 256) {
            float v = lsf[t] + lsf[256 + t] + lsf[512 + t] + lsf[768 + t];
            Lp[((long)z * 16 + by) * 4096 + bx * 256 + t] = v;
        }
    } else {
        #pragma unroll
        for (int i = 0; i < 8; ++i)
            #pragma unroll
            for (int n = 0; n < 4; ++n) {
                const int col = col0 + n * 16 + lr;
                #pragma unroll
                for (int r = 0; r < 4; ++r)
                    Cz[(long)(row0 + i * 16 + rq + r) * ldc + col] = (bf16)acc[i][n][r];
            }
    }
}

// =====================================================================
// PV GEMM: O[64 x 512] per block = P[64 x 4096] * V (via Vt[512][4096]),
// normalized by 1/rowsum from Lp. 512 threads, 8 waves (wave w: D-cols w*64).
// P read exactly once; V streamed (L3-resident). 2-tile-deep counted vmcnt.
// LDS: Bs dbuf 128KB + As dbuf 16KB + linv. No exp, no shuffles in loop.
// =====================================================================
__global__ __launch_bounds__(512, 1) void k_pv(
    const bf16* __restrict__ P, const float* __restrict__ Lp,
    const bf16* __restrict__ Vt, bf16* __restrict__ O) {
    __shared__ bf16 Bs[2][512 * 64];
    __shared__ bf16 As[2][64 * 64];
    __shared__ float linv[64];
    const int t = threadIdx.x;
    const int w = t >> 6, l = t & 63, lr = l & 15, lg = l >> 4;
    const int lr7 = lr & 7;
    const int sr = t >> 3, sc8 = t & 7, sr7 = sr & 7;
    const long z = blockIdx.y;
    const int bx = blockIdx.x;

    const bf16* Pg = P + z * ((long)4096 * 4096) + (long)(bx * 64 + sr) * 4096 + (sc8 ^ sr7) * 8;
    const bf16* Vg = Vt + z * ((long)512 * 4096) + (long)sr * 4096 + (sc8 ^ sr7) * 8;

    auto issue = [&](int tile, int buf) {
        gload_lds16(Pg + tile * 64, As[buf] + t * 8);
        #pragma unroll
        for (int u = 0; u < 8; ++u)
            gload_lds16(Vg + (long)u * 64 * 4096 + tile * 64, Bs[buf] + u * 4096 + t * 8);
    };

    // 1/rowsum: threads 0..63 sum the 16 col-tile partials for their row
    if (t < 64) {
        const float* lpp = Lp + z * 16 * 4096 + bx * 64 + t;
        float s = 0.f;
        #pragma unroll
        for (int j = 0; j < 16; ++j) s += lpp[j * 4096];
        linv[t] = 1.f / s;
    }

    f32x4 acc[4][4];
    #pragma unroll
    for (int i = 0; i < 4; ++i)
        #pragma unroll
        for (int n = 0; n < 4; ++n) acc[i][n] = f32x4{0.f, 0.f, 0.f, 0.f};

    issue(0, 0);
    issue(1, 1);

    for (int ti = 0; ti < 64; ++ti) {
        if (ti < 63) { asm volatile("s_waitcnt vmcnt(9)" ::: "memory"); }
        else         { asm volatile("s_waitcnt vmcnt(0)" ::: "memory"); }
        __builtin_amdgcn_s_barrier();
        asm volatile("" ::: "memory");

        const bf16* Asb = As[ti & 1];
        const bf16* Bsb = Bs[ti & 1];
        __builtin_amdgcn_s_setprio(1);
        #pragma unroll
        for (int kk = 0; kk < 2; ++kk) {
            bf16x8 af[4], bfv[4];
            #pragma unroll
            for (int mi = 0; mi < 4; ++mi)
                af[mi] = *(const bf16x8*)(Asb + (mi * 16 + lr) * 64 + (((kk * 4 + lg) ^ lr7) * 8));
            #pragma unroll
            for (int n = 0; n < 4; ++n)
                bfv[n] = *(const bf16x8*)(Bsb + (w * 64 + n * 16 + lr) * 64 + (((kk * 4 + lg) ^ lr7) * 8));
            #pragma unroll
            for (int mi = 0; mi < 4; ++mi)
                #pragma unroll
                for (int n = 0; n < 4; ++n)
                    acc[mi][n] = __builtin_amdgcn_mfma_f32_16x16x32_bf16(af[mi], bfv[n], acc[mi][n], 0, 0, 0);
        }
        __builtin_amdgcn_s_setprio(0);

        __builtin_amdgcn_s_barrier();
        asm volatile("" ::: "memory");
        if (ti < 62) issue(ti + 2, ti & 1);
    }

    bf16* Oz = O + z * ((long)4096 * 512);
    #pragma unroll
    for (int mi = 0; mi < 4; ++mi) {
        float4 lv = *(const float4*)&linv[mi * 16 + lg * 4];
        #pragma unroll
        for (int n = 0; n < 4; ++n) {
            const long base = (long)(bx * 64 + mi * 16 + lg * 4) * 512 + w * 64 + n * 16 + lr;
            Oz[base]        = (bf16)(acc[mi][n][0] * lv.x);
            Oz[base + 512]  = (bf16)(acc[mi][n][1] * lv.y);
            Oz[base + 1024] = (bf16)(acc[mi][n][2] * lv.z);
            Oz[base + 1536] = (bf16)(acc[mi][n][3] * lv.w);
        }
    }
}

// =====================================================================
// 256x128 tile, BK=64, 8-wave (4M x 2N), 8-phase, counted vmcnt.
// EPI 2: f32 + bias store (proj).
// =====================================================================
#define PH128(nh, kk, S_, WN)                                                      \
  {                                                                                \
    if ((nh) == 0) {                                                               \
      _Pragma("unroll")                                                            \
      for (int i = 0; i < 4; ++i) {                                                \
        int row = wm * 64 + i * 16 + lr;                                           \
        int cg = lg ^ (row & 3);                                                   \
        af[i] = *(const bf16x8*)(AsT + (kk) * 8192 + row * 32 + cg * 8);           \
      }                                                                            \
    }                                                                              \
    _Pragma("unroll")                                                              \
    for (int j = 0; j < 2; ++j) {                                                  \
      int row = wn * 64 + ((nh) * 2 + j) * 16 + lr;                                \
      int cg = lg ^ (row & 3);                                                     \
      bfr[j] = *(const bf16x8*)(BsT + (kk) * 4096 + row * 32 + cg * 8);            \
    }                                                                              \
    if ((S_) >= 0) issue_unit(S_);                                                 \
    __builtin_amdgcn_s_barrier();                                                  \
    asm volatile("" ::: "memory");                                                 \
    __builtin_amdgcn_s_setprio(1);                                                 \
    _Pragma("unroll")                                                              \
    for (int i = 0; i < 4; ++i)                                                    \
      _Pragma("unroll")                                                            \
      for (int j = 0; j < 2; ++j)                                                  \
        acc[i][(nh) * 2 + j] =                                                     \
            __builtin_amdgcn_mfma_f32_16x16x32_bf16(af[i], bfr[j],                 \
                                                    acc[i][(nh) * 2 + j], 0, 0, 0);\
    __builtin_amdgcn_s_setprio(0);                                                 \
    if constexpr ((WN) >= 0)                                                       \
      asm volatile("s_waitcnt vmcnt(%0)" ::"i"(WN) : "memory");                    \
    __builtin_amdgcn_s_barrier();                                                  \
    asm volatile("" ::: "memory");                                                 \
  }

template <int EPI>
__global__ __launch_bounds__(512, 2) void gemm_n128(
    const bf16* __restrict__ A, int lda, long aZ,
    const bf16* __restrict__ B, int ldb, long bZ,
    void* __restrict__ Cvp, int ldc, long cZ, int K,
    const float* __restrict__ bias) {
    __shared__ bf16 As[2 * 2 * 256 * 32];   // 64 KB
    __shared__ bf16 Bs[2 * 2 * 128 * 32];   // 32 KB
    const int t = threadIdx.x;
    const int wid = t >> 6, l = t & 63;
    const int wm = wid >> 1, wn = wid & 1;   // 4M x 2N waves, wave tile 64x64
    const int lr = l & 15;
    const int lg = l >> 4;
    const long z = blockIdx.z;

    const int gx = gridDim.x;
    int nwg = gx * gridDim.y;
    int flat = blockIdx.y * gx + blockIdx.x;
    if ((nwg & 7) == 0) { int qq = nwg >> 3; flat = (flat & 7) * qq + (flat >> 3); }
    const int bx = flat % gx, by = flat / gx;

    const bf16* Ab = A + z * aZ + (long)bx * 256 * lda;
    const bf16* Bb = B + z * bZ + (long)by * 128 * ldb;

    const int NT = K >> 6;
    const int NT4 = NT << 2;

    f32x4 acc[4][4];
    #pragma unroll
    for (int i = 0; i < 4; ++i)
        #pragma unroll
        for (int n = 0; n < 4; ++n) acc[i][n] = f32x4{0.f, 0.f, 0.f, 0.f};

    const int srow = t >> 2;       // 0..127
    const int scg0 = t & 3;

    auto issue_unit = [&](int s) {
        int ti = s >> 2, idx = s & 3;
        int kh = idx >> 1, isB = idx & 1;
        int k0 = ti * 64 + kh * 32;
        if (isB) {
            bf16* lp = Bs + ((ti & 1) * 2 + kh) * 4096;
            int cg = scg0 ^ (srow & 3);
            gload_lds16(Bb + (long)srow * ldb + k0 + cg * 8, lp + t * 8);
        } else {
            bf16* lp = As + ((ti & 1) * 2 + kh) * 8192;
            #pragma unroll
            for (int j = 0; j < 2; ++j) {
                int row = j * 128 + srow;
                int cg = scg0 ^ (row & 3);
                gload_lds16(Ab + (long)row * lda + k0 + cg * 8, lp + (j * 512 + t) * 8);
            }
        }
    };

    #pragma unroll
    for (int s = 0; s < 6; ++s) issue_unit(s);
    asm volatile("s_waitcnt vmcnt(6)" ::: "memory");
    __builtin_amdgcn_s_barrier();
    asm volatile("" ::: "memory");

    bf16x8 bfr[2], af[4];

    for (int ti = 0; ti < NT - 2; ++ti) {
        const bf16* AsT = As + (ti & 1) * 16384;
        const bf16* BsT = Bs + (ti & 1) * 8192;
        const int sb = 4 * ti + 6;
        PH128(0, 0, sb + 0, -1)
        PH128(1, 0, sb + 1, 6)
        PH128(0, 1, sb + 2, -1)
        PH128(1, 1, sb + 3, 6)
    }
    {
        const bf16* AsT = As + ((NT - 2) & 1) * 16384;
        const bf16* BsT = Bs + ((NT - 2) & 1) * 8192;
        PH128(0, 0, NT4 - 2, -1)
        PH128(1, 0, NT4 - 1, 6)
        PH128(0, 1, -1, -1)
        PH128(1, 1, -1, 3)
    }
    {
        const bf16* AsT = As + ((NT - 1) & 1) * 16384;
        const bf16* BsT = Bs + ((NT - 1) & 1) * 8192;
        PH128(0, 0, -1, -1)
        PH128(1, 0, -1, 0)
        PH128(0, 1, -1, -1)
        PH128(1, 1, -1, -1)
    }

    const int row0 = bx * 256 + wm * 64;
    const int col0 = by * 128 + wn * 64;
    const int rq = lg * 4;
    if (EPI == 2) {
        float* C = (float*)Cvp + z * cZ;
        #pragma unroll
        for (int i = 0; i < 4; ++i)
            #pragma unroll
            for (int n = 0; n < 4; ++n) {
                const int col = col0 + n * 16 + lr;
                #pragma unroll
                for (int r = 0; r < 4; ++r)
                    C[(long)(row0 + i * 16 + rq + r) * ldc + col] = acc[i][n][r] + bias[col];
            }
    } else {
        bf16* C = (bf16*)Cvp + z * cZ;
        #pragma unroll
        for (int i = 0; i < 4; ++i)
            #pragma unroll
            for (int n = 0; n < 4; ++n) {
                const int col = col0 + n * 16 + lr;
                #pragma unroll
                for (int r = 0; r < 4; ++r)
                    C[(long)(row0 + i * 16 + rq + r) * ldc + col] = (bf16)acc[i][n][r];
            }
    }
}

// ---------------- proj-out [nt][512] f32 -> NCHW + residual ----------------
__global__ __launch_bounds__(256) void k_final(const float* __restrict__ pb,
                                               const float* __restrict__ x,
                                               float* __restrict__ out) {
    __shared__ float tile[64][65];
    const int bid = blockIdx.x;
    const int n = bid >> 9, rem = bid & 511;
    const int s0 = (rem >> 3) * 64, c0 = (rem & 7) * 64;
    const int tid = threadIdx.x;
    #pragma unroll
    for (int i = 0; i < 16; ++i) {
        const int sl = (tid >> 6) * 16 + i;
        const int cl = tid & 63;
        tile[sl][cl] = pb[((long)(n * 4096 + s0 + sl)) * 512 + c0 + cl];
    }
    __syncthreads();
    #pragma unroll
    for (int i = 0; i < 16; ++i) {
        const int cl = (tid >> 6) * 16 + i;
        const int sl = tid & 63;
        const long oi = ((long)(n * 512 + c0 + cl)) * 4096 + s0 + sl;
        out[oi] = tile[sl][cl] + x[oi];
    }
}

extern "C" void kernel_launch(void* const* d_in, const int* in_sizes, int n_in,
                              void* d_out, int out_size, void* d_ws, size_t ws_size,
                              hipStream_t stream) {
    const float* x     = (const float*)d_in[0];
    const float* gnw   = (const float*)d_in[1];
    const float* gnb   = (const float*)d_in[2];
    const float* qkvw  = (const float*)d_in[3];
    const float* projw = (const float*)d_in[4];
    const float* projb = (const float*)d_in[5];

    char* ws = (char*)d_ws;
    size_t off = 0;
    auto alloc = [&](size_t bytes) {
        void* p = ws + off;
        off += (bytes + 255) & ~(size_t)255;
        return p;
    };
    bf16*   qwb   = (bf16*)alloc((size_t)1536 * 512 * 2);
    bf16*   pwb   = (bf16*)alloc((size_t)512 * 512 * 2);
    float2* stats = (float2*)alloc((size_t)128 * 8);
    bf16*   tbuf  = (bf16*)alloc((size_t)16384 * 512 * 2);   // tokens, later O
    bf16*   qkv   = (bf16*)alloc((size_t)16384 * 1536 * 2);
    bf16*   Vt    = (bf16*)alloc((size_t)4 * 512 * 4096 * 2);
    float*  Lpart = (float*)alloc((size_t)4 * 16 * 4096 * 4);
    const size_t SSZ = (size_t)4096 * 4096 * 2;              // one batch of P (bf16)
    const size_t fixed = off;
    int g = 1;
    if (ws_size >= fixed + 4 * SSZ) g = 4;
    else if (ws_size >= fixed + 2 * SSZ) g = 2;
    bf16* Sbuf = (bf16*)alloc(g * SSZ);

    k_gnstats<<<128, 256, 0, stream>>>(x, stats);
    k_norm_t<<<2048, 256, 0, stream>>>(x, gnw, gnb, stats, tbuf);
    k_convw<<<4096, 256, 0, stream>>>(qkvw, projw, qwb, pwb);

    // qkv = t * qkvw^T   [16384 x 1536], 8-phase 256^2 kernel
    gemm256<0><<<dim3(64, 6, 1), 512, 0, stream>>>(
        tbuf, 512, 0, qwb, 512, 0, qkv, 1536, 0, 512, nullptr);

    k_vt<<<2048, 256, 0, stream>>>(qkv, Vt);

    const long TS = (long)4096 * 1536;
    for (int g0 = 0; g0 < 4; g0 += g) {
        // P = exp2(q k^T) (log2e & 1/sqrt(512) folded into q weights) + row-sum partials
        gemm256<1><<<dim3(16, 16, g), 512, 0, stream>>>(
            qkv + (long)g0 * TS, 1536, TS,
            qkv + (long)g0 * TS + 512, 1536, TS,
            Sbuf, 4096, (long)4096 * 4096, 512, Lpart);
        // O = (P * V) / rowsum
        k_pv<<<dim3(64, g), 512, 0, stream>>>(
            Sbuf, Lpart, Vt + (long)g0 * 512 * 4096, tbuf + (long)g0 * 4096 * 512);
    }

    // proj: [16384 x 512] f32 + bias, into Sbuf (reused as f32 buffer)
    gemm_n128<2><<<dim3(64, 4, 1), 512, 0, stream>>>(
        tbuf, 512, 0, pwb, 512, 0, (float*)Sbuf, 512, 0, 512, projb);

    // transpose back + residual
    k_final<<<2048, 256, 0, stream>>>((float*)Sbuf, x, (float*)d_out);
}